// Round 1
// baseline (82.125 us; speedup 1.0000x reference)
//
#include <hip/hip_runtime.h>

// ButterflyRotation: out = 12 butterfly layers over rows of 4096 fp32.
// Single fused pass: global -> LDS (swizzled) -> 6 radix-4 stages -> global.

#define DIM   4096
#define LAYERS 12
#define BATCH 8192
#define NANG  2048            // angles per layer = DIM/2
#define QROW  1024            // float4 quads per row
#define BLOCK 128             // 2 waves
#define ROWS_PER_BLOCK 2

typedef unsigned int u32;

// Quad-level LDS swizzle (involution): spreads bank-quads so every stage's
// ds_read_b128/ds_write_b128 pattern is <=2-way (free).
__device__ __forceinline__ int swz(int q) {
    return q ^ ((q >> 3) & 7) ^ ((q >> 6) & 7);
}

__device__ __forceinline__ void rot(float& xl, float& xr, float c, float s) {
    float nl = c * xl + s * xr;
    float nr = c * xr - s * xl;
    xl = nl; xr = nr;
}

__global__ void __launch_bounds__(256) cs_kernel(const float* __restrict__ angles,
                                                 float2* __restrict__ cs, int n) {
    int i = blockIdx.x * blockDim.x + threadIdx.x;
    if (i < n) {
        float a = angles[i];
        cs[i] = make_float2(cosf(a), sinf(a));
    }
}

__global__ void __launch_bounds__(BLOCK) butterfly_kernel(const float* __restrict__ x,
                                                          const float2* __restrict__ cs,
                                                          float* __restrict__ out) {
    __shared__ float4 smem[ROWS_PER_BLOCK * QROW];   // 32 KiB: 2 rows
    const int tid  = threadIdx.x;
    const int wave = tid >> 6;
    const int lane = tid & 63;
    const long row0 = (long)blockIdx.x * ROWS_PER_BLOCK;

    // ---- stage rows into LDS: linear dest, pre-swizzled global source ----
    {
        const float* src = x + (row0 + wave) * DIM;
        float4* dst = smem + wave * QROW;
        #pragma unroll
        for (int j = 0; j < 16; ++j) {
            int g = swz(j * 64 + lane);   // LDS slot (j*64+lane) holds logical quad swz(slot)
            __builtin_amdgcn_global_load_lds(
                (const __attribute__((address_space(1))) u32*)(src + g * 4),
                (__attribute__((address_space(3))) u32*)(dst + j * 64),
                16, 0, 0);
        }
    }
    __syncthreads();   // drains vmcnt(0) for all waves

    float4* const s0 = smem;
    float4* const s1 = smem + QROW;

    // ---- stage 0: layers 0,1 (element strides 1,2) -- radix-4 inside each quad group
    {
        const float2* tab0 = cs;
        const float2* tab1 = cs + NANG;
        #pragma unroll
        for (int it = 0; it < 2; ++it) {
            const int v  = it * BLOCK + tid;            // unit id, 16 contiguous elements
            const int m0 = swz(4*v+0), m1 = swz(4*v+1), m2 = swz(4*v+2), m3 = swz(4*v+3);
            const float4* pE = (const float4*)(tab0 + 8*v);  // 8 float2 = 4 float4
            const float4* pF = (const float4*)(tab1 + 8*v);
            float4 E0 = pE[0], E1 = pE[1], E2 = pE[2], E3 = pE[3];
            float4 F0 = pF[0], F1 = pF[1], F2 = pF[2], F3 = pF[3];
            #pragma unroll
            for (int r = 0; r < ROWS_PER_BLOCK; ++r) {
                float4* sr = (r == 0) ? s0 : s1;
                float4 r0 = sr[m0], r1 = sr[m1], r2 = sr[m2], r3 = sr[m3];
                // layer 0: pairs (x,y),(z,w); layer 1: pairs (x,z),(y,w)
                rot(r0.x, r0.y, E0.x, E0.y); rot(r0.z, r0.w, E0.z, E0.w);
                rot(r0.x, r0.z, F0.x, F0.y); rot(r0.y, r0.w, F0.z, F0.w);
                rot(r1.x, r1.y, E1.x, E1.y); rot(r1.z, r1.w, E1.z, E1.w);
                rot(r1.x, r1.z, F1.x, F1.y); rot(r1.y, r1.w, F1.z, F1.w);
                rot(r2.x, r2.y, E2.x, E2.y); rot(r2.z, r2.w, E2.z, E2.w);
                rot(r2.x, r2.z, F2.x, F2.y); rot(r2.y, r2.w, F2.z, F2.w);
                rot(r3.x, r3.y, E3.x, E3.y); rot(r3.z, r3.w, E3.z, E3.w);
                rot(r3.x, r3.z, F3.x, F3.y); rot(r3.y, r3.w, F3.z, F3.w);
                sr[m0] = r0; sr[m1] = r1; sr[m2] = r2; sr[m3] = r3;
            }
        }
    }
    __syncthreads();

    // ---- stages 1..5: layers (2st, 2st+1), element stride s = 4^st ----
    for (int st = 1; st < 6; ++st) {
        const int l   = 2 * st;
        const int s   = 1 << l;        // element stride of layer l
        const int qsl = l - 2;         // log2(quads per stride)
        const int qs  = 1 << qsl;
        const float2* tab0 = cs + l * NANG;
        const float2* tab1 = tab0 + NANG;
        #pragma unroll
        for (int it = 0; it < 2; ++it) {
            const int v   = it * BLOCK + tid;
            const int sb  = v >> qsl;           // superblock (4s elements)
            const int off = v & (qs - 1);       // quad offset within stride run
            const int qbase = sb * s + off;     // in quads
            const int m0 = swz(qbase),          m1 = swz(qbase + qs),
                      m2 = swz(qbase + 2*qs),   m3 = swz(qbase + 3*qs);
            const int a = 2 * sb * s + 4 * off; // angle index (element units)
            const float4* pA = (const float4*)(tab0 + a);      // layer l, pair (r0,r1)
            const float4* pB = (const float4*)(tab0 + a + s);  // layer l, pair (r2,r3)
            const float4* pC = (const float4*)(tab1 + a);      // layer l+1, pair (r0,r2)
            const float4* pD = (const float4*)(tab1 + a + s);  // layer l+1, pair (r1,r3)
            float4 A0 = pA[0], A1 = pA[1];
            float4 B0 = pB[0], B1 = pB[1];
            float4 C0 = pC[0], C1 = pC[1];
            float4 D0 = pD[0], D1 = pD[1];
            #pragma unroll
            for (int r = 0; r < ROWS_PER_BLOCK; ++r) {
                float4* sr = (r == 0) ? s0 : s1;
                float4 r0 = sr[m0], r1 = sr[m1], r2 = sr[m2], r3 = sr[m3];
                // layer l
                rot(r0.x, r1.x, A0.x, A0.y); rot(r0.y, r1.y, A0.z, A0.w);
                rot(r0.z, r1.z, A1.x, A1.y); rot(r0.w, r1.w, A1.z, A1.w);
                rot(r2.x, r3.x, B0.x, B0.y); rot(r2.y, r3.y, B0.z, B0.w);
                rot(r2.z, r3.z, B1.x, B1.y); rot(r2.w, r3.w, B1.z, B1.w);
                // layer l+1
                rot(r0.x, r2.x, C0.x, C0.y); rot(r0.y, r2.y, C0.z, C0.w);
                rot(r0.z, r2.z, C1.x, C1.y); rot(r0.w, r2.w, C1.z, C1.w);
                rot(r1.x, r3.x, D0.x, D0.y); rot(r1.y, r3.y, D0.z, D0.w);
                rot(r1.z, r3.z, D1.x, D1.y); rot(r1.w, r3.w, D1.z, D1.w);
                sr[m0] = r0; sr[m1] = r1; sr[m2] = r2; sr[m3] = r3;
            }
        }
        __syncthreads();
    }

    // ---- store: swizzled LDS read (conflict-free), coalesced global write ----
    {
        float* dst0 = out + row0 * DIM;
        float* dst1 = dst0 + DIM;
        #pragma unroll
        for (int j = 0; j < 8; ++j) {
            const int q = j * BLOCK + tid;   // logical quad
            const int p = swz(q);
            float4 v0 = s0[p];
            float4 v1 = s1[p];
            *(float4*)(dst0 + q * 4) = v0;
            *(float4*)(dst1 + q * 4) = v1;
        }
    }
}

extern "C" void kernel_launch(void* const* d_in, const int* in_sizes, int n_in,
                              void* d_out, int out_size, void* d_ws, size_t ws_size,
                              hipStream_t stream) {
    (void)in_sizes; (void)n_in; (void)out_size; (void)ws_size;
    const float* x      = (const float*)d_in[0];
    const float* angles = (const float*)d_in[1];
    float* out = (float*)d_out;
    float2* cs = (float2*)d_ws;   // 12*2048*8 B = 196 KiB scratch

    const int n = LAYERS * NANG;
    cs_kernel<<<(n + 255) / 256, 256, 0, stream>>>(angles, cs, n);
    butterfly_kernel<<<BATCH / ROWS_PER_BLOCK, BLOCK, 0, stream>>>(x, cs, out);
}

// Round 2
// 73.685 us; speedup vs baseline: 1.1145x; 1.1145x over previous
//
#include <hip/hip_runtime.h>

// ButterflyRotation: out = 12 butterfly layers over rows of 4096 fp32.
// Single fused pass: global -> LDS (swizzled) -> 6 radix-4 stages -> global.
// R2: 256-thread blocks (4 waves), 2 rows/block, 32 KiB LDS -> 20 waves/CU.

#define DIM   4096
#define LAYERS 12
#define BATCH 8192
#define NANG  2048            // angles per layer = DIM/2
#define QROW  1024            // float4 quads per row
#define BLOCK 256             // 4 waves
#define ROWS_PER_BLOCK 2

typedef unsigned int u32;

// Quad-level LDS swizzle (involution): spreads bank-quads so stage reads
// are <=2-way (free). Only low 3 bits change (from bits 3-5 ^ 6-8).
__device__ __forceinline__ int swz(int q) {
    return q ^ ((q >> 3) & 7) ^ ((q >> 6) & 7);
}

__device__ __forceinline__ void rot(float& xl, float& xr, float c, float s) {
    float nl = c * xl + s * xr;
    float nr = c * xr - s * xl;
    xl = nl; xr = nr;
}

__global__ void __launch_bounds__(256) cs_kernel(const float* __restrict__ angles,
                                                 float2* __restrict__ cs, int n) {
    int i = blockIdx.x * blockDim.x + threadIdx.x;
    if (i < n) {
        float a = angles[i];
        cs[i] = make_float2(cosf(a), sinf(a));
    }
}

__global__ void __launch_bounds__(BLOCK) butterfly_kernel(const float* __restrict__ x,
                                                          const float2* __restrict__ cs,
                                                          float* __restrict__ out) {
    __shared__ float4 smem[ROWS_PER_BLOCK * QROW];   // 32 KiB: 2 rows
    const int tid  = threadIdx.x;
    const int wave = tid >> 6;
    const int lane = tid & 63;
    const long row0 = (long)blockIdx.x * ROWS_PER_BLOCK;

    // ---- stage rows into LDS: linear dest, pre-swizzled global source ----
    // wave w: row = w>>1, half-row = w&1 (512 quads = 8 x 64-lane x 16B)
    {
        const float* src = x + (row0 + (wave >> 1)) * DIM;
        float4* dst = smem + (wave >> 1) * QROW + (wave & 1) * 512;
        #pragma unroll
        for (int j = 0; j < 8; ++j) {
            int slot = (wave & 1) * 512 + j * 64 + lane;   // logical slot in row
            int g = swz(slot);                             // logical quad stored here
            __builtin_amdgcn_global_load_lds(
                (const __attribute__((address_space(1))) u32*)(src + g * 4),
                (__attribute__((address_space(3))) u32*)(dst + j * 64),
                16, 0, 0);
        }
    }
    __syncthreads();   // drains vmcnt(0) for all waves

    float4* const s0 = smem;
    float4* const s1 = smem + QROW;

    // ---- stage 0: layers 0,1 (element strides 1,2) -- radix-4 inside 4 quads
    {
        const float2* tab0 = cs;
        const float2* tab1 = cs + NANG;
        const int v  = tid;                          // unit id: 16 contiguous elems
        const int m0 = swz(4*v+0), m1 = swz(4*v+1), m2 = swz(4*v+2), m3 = swz(4*v+3);
        const float4* pE = (const float4*)(tab0 + 8*v);  // 8 float2 = 4 float4
        const float4* pF = (const float4*)(tab1 + 8*v);
        float4 E0 = pE[0], E1 = pE[1], E2 = pE[2], E3 = pE[3];
        float4 F0 = pF[0], F1 = pF[1], F2 = pF[2], F3 = pF[3];
        #pragma unroll
        for (int r = 0; r < ROWS_PER_BLOCK; ++r) {
            float4* sr = (r == 0) ? s0 : s1;
            float4 r0 = sr[m0], r1 = sr[m1], r2 = sr[m2], r3 = sr[m3];
            rot(r0.x, r0.y, E0.x, E0.y); rot(r0.z, r0.w, E0.z, E0.w);
            rot(r0.x, r0.z, F0.x, F0.y); rot(r0.y, r0.w, F0.z, F0.w);
            rot(r1.x, r1.y, E1.x, E1.y); rot(r1.z, r1.w, E1.z, E1.w);
            rot(r1.x, r1.z, F1.x, F1.y); rot(r1.y, r1.w, F1.z, F1.w);
            rot(r2.x, r2.y, E2.x, E2.y); rot(r2.z, r2.w, E2.z, E2.w);
            rot(r2.x, r2.z, F2.x, F2.y); rot(r2.y, r2.w, F2.z, F2.w);
            rot(r3.x, r3.y, E3.x, E3.y); rot(r3.z, r3.w, E3.z, E3.w);
            rot(r3.x, r3.z, F3.x, F3.y); rot(r3.y, r3.w, F3.z, F3.w);
            sr[m0] = r0; sr[m1] = r1; sr[m2] = r2; sr[m3] = r3;
        }
    }
    __syncthreads();

    // ---- stages 1..5: layers (2st, 2st+1), element stride s = 4^st ----
    for (int st = 1; st < 6; ++st) {
        const int l   = 2 * st;
        const int s   = 1 << l;        // element stride of layer l
        const int qsl = l - 2;         // log2(quad stride)
        const int qs  = 1 << qsl;
        const float2* tab0 = cs + l * NANG;
        const float2* tab1 = tab0 + NANG;
        const int v   = tid;
        const int sb  = v >> qsl;           // superblock index
        const int off = v & (qs - 1);       // quad offset within stride run
        const int qbase = sb * s + off;     // first quad of the radix-4 unit
        const int m0 = swz(qbase),          m1 = swz(qbase + qs),
                  m2 = swz(qbase + 2*qs),   m3 = swz(qbase + 3*qs);
        const int a = 2 * sb * s + 4 * off; // angle index (element units)
        const float4* pA = (const float4*)(tab0 + a);      // layer l, pair (r0,r1)
        const float4* pB = (const float4*)(tab0 + a + s);  // layer l, pair (r2,r3)
        const float4* pC = (const float4*)(tab1 + a);      // layer l+1, pair (r0,r2)
        const float4* pD = (const float4*)(tab1 + a + s);  // layer l+1, pair (r1,r3)
        float4 A0 = pA[0], A1 = pA[1];
        float4 B0 = pB[0], B1 = pB[1];
        float4 C0 = pC[0], C1 = pC[1];
        float4 D0 = pD[0], D1 = pD[1];
        #pragma unroll
        for (int r = 0; r < ROWS_PER_BLOCK; ++r) {
            float4* sr = (r == 0) ? s0 : s1;
            float4 r0 = sr[m0], r1 = sr[m1], r2 = sr[m2], r3 = sr[m3];
            // layer l
            rot(r0.x, r1.x, A0.x, A0.y); rot(r0.y, r1.y, A0.z, A0.w);
            rot(r0.z, r1.z, A1.x, A1.y); rot(r0.w, r1.w, A1.z, A1.w);
            rot(r2.x, r3.x, B0.x, B0.y); rot(r2.y, r3.y, B0.z, B0.w);
            rot(r2.z, r3.z, B1.x, B1.y); rot(r2.w, r3.w, B1.z, B1.w);
            // layer l+1
            rot(r0.x, r2.x, C0.x, C0.y); rot(r0.y, r2.y, C0.z, C0.w);
            rot(r0.z, r2.z, C1.x, C1.y); rot(r0.w, r2.w, C1.z, C1.w);
            rot(r1.x, r3.x, D0.x, D0.y); rot(r1.y, r3.y, D0.z, D0.w);
            rot(r1.z, r3.z, D1.x, D1.y); rot(r1.w, r3.w, D1.z, D1.w);
            sr[m0] = r0; sr[m1] = r1; sr[m2] = r2; sr[m3] = r3;
        }
        __syncthreads();
    }

    // ---- store: swizzled LDS read, coalesced 16B global writes ----
    {
        float* dst0 = out + row0 * DIM;
        float* dst1 = dst0 + DIM;
        #pragma unroll
        for (int j = 0; j < 4; ++j) {
            const int q = j * BLOCK + tid;   // logical quad
            const int p = swz(q);
            float4 v0 = s0[p];
            float4 v1 = s1[p];
            *(float4*)(dst0 + q * 4) = v0;
            *(float4*)(dst1 + q * 4) = v1;
        }
    }
}

extern "C" void kernel_launch(void* const* d_in, const int* in_sizes, int n_in,
                              void* d_out, int out_size, void* d_ws, size_t ws_size,
                              hipStream_t stream) {
    (void)in_sizes; (void)n_in; (void)out_size; (void)ws_size;
    const float* x      = (const float*)d_in[0];
    const float* angles = (const float*)d_in[1];
    float* out = (float*)d_out;
    float2* cs = (float2*)d_ws;   // 12*2048*8 B = 196 KiB scratch

    const int n = LAYERS * NANG;
    cs_kernel<<<(n + 255) / 256, 256, 0, stream>>>(angles, cs, n);
    butterfly_kernel<<<BATCH / ROWS_PER_BLOCK, BLOCK, 0, stream>>>(x, cs, out);
}